// Round 4
// baseline (3423.001 us; speedup 1.0000x reference)
//
#include <hip/hip_runtime.h>
#include <hip/hip_bf16.h>

typedef __hip_bfloat16 bf16;
typedef unsigned short u16;
typedef unsigned int u32;
typedef __attribute__((ext_vector_type(8))) short bf16x8;
typedef __attribute__((ext_vector_type(4))) float f32x4;

// Problem constants
#define BATCH 256
#define TLEN 100
#define HDIM 1024
#define G4 4096
#define OUT_HT (BATCH * TLEN * HDIM)    // float offset of c4 section in d_out

// Workspace layout (byte offsets).
#define WS_WP 0u
#define WS_BIAS 59244544u   // f32 [4][4096]
#define WS_XT 59310080u     // bf16 chunk-major [100][256][64], swizzle baked
#define WS_H 62586880u      // bf16 [8 slots][16 chunks][256][64], swizzle baked
#define WS_BAR (WS_H + 4194304u)

__device__ __forceinline__ float sigm(float x) { return 1.0f / (1.0f + __expf(-x)); }
__device__ __forceinline__ float tanh_(float x) { return 2.0f / (1.0f + __expf(-2.0f * x)) - 1.0f; }

__device__ __forceinline__ void gl_lds16(const void* g, void* l) {
  __builtin_amdgcn_global_load_lds((const __attribute__((address_space(1))) u32*)g,
                                   (__attribute__((address_space(3))) u32*)l, 16, 0, 0);
}

// Lean global barrier (proven R2/R3): monotone release epoch, one ACQ_REL RMW per WG.
__device__ __forceinline__ void gbar(u32* arrive, u32* release, u32 epoch, int tid) {
  __syncthreads();
  if (tid == 0) {
    u32 old = __hip_atomic_fetch_add(arrive, 1u, __ATOMIC_ACQ_REL, __HIP_MEMORY_SCOPE_AGENT);
    if (old == 255u) {
      __hip_atomic_store(arrive, 0u, __ATOMIC_RELAXED, __HIP_MEMORY_SCOPE_AGENT);
      __hip_atomic_store(release, epoch, __ATOMIC_RELEASE, __HIP_MEMORY_SCOPE_AGENT);
    } else {
      while (__hip_atomic_load(release, __ATOMIC_RELAXED, __HIP_MEMORY_SCOPE_AGENT) < epoch)
        __builtin_amdgcn_s_sleep(2);
      __builtin_amdgcn_fence(__ATOMIC_ACQUIRE, "agent");
    }
  }
  __syncthreads();
}

// ---------- setup kernels ----------

__global__ void pack_w(const float* __restrict__ wih, const float* __restrict__ whh,
                       bf16* __restrict__ dst, int NC, int din) {
  int i = blockIdx.x * 256 + threadIdx.x;
  if (i >= 32 * NC * 128 * 64) return;
  int k6 = i & 63;
  int r = (i >> 6) & 127;
  int jc = i >> 13;
  int c = jc % NC;
  int j = jc / NC;
  int grow = ((r >> 5) << 10) + j * 32 + (r & 31);
  int k = c * 64 + k6;
  float v = (k < din) ? wih[grow * din + k] : whh[(grow << 10) + (k - din)];
  dst[(jc << 13) + (r << 6) + (k6 ^ ((r & 7) << 3))] = __float2bfloat16(v);
}

__global__ void pack_bias(const float* __restrict__ a, const float* __restrict__ b,
                          float* __restrict__ dst) {
  int i = blockIdx.x * 256 + threadIdx.x;
  if (i < G4) dst[i] = a[i] + b[i];
}

__global__ void pack_x(const float* __restrict__ x, bf16* __restrict__ xT) {
  int i = blockIdx.x * 256 + threadIdx.x;
  if (i >= TLEN * BATCH * 64) return;
  int k = i & 63;
  int b = (i >> 6) & 255;
  int t = i >> 14;
  xT[(t << 14) + (b << 6) + (k ^ ((b & 7) << 3))] = __float2bfloat16(x[(b * TLEN + t) * 64 + k]);
}

// ---------- main persistent pipelined kernel ----------
// 256 WGs x 512 threads. A ring: 4 slots, lead 2. B ring: 5 slots, lead 4.
// Per-chunk issue order A-then-B; uniform s_waitcnt vmcnt(10) (age-derived).
// Tail uses clamped dummy issues so the vmcnt accounting stays uniform.
// out[] stores are non-temporal: keep weights resident in Infinity Cache.

__global__ void __launch_bounds__(512, 2)
lstm_main(const u16* __restrict__ Wp, const float* __restrict__ biasc,
          const u16* __restrict__ xT, u16* __restrict__ hbuf,
          float* __restrict__ out, u32* __restrict__ barr) {
  // A bufs: u16 [4][8192] @ 0 (64KB). B bufs: u16 [5][8192] @ 32768 (80KB). Total 144KB.
  __shared__ __align__(16) u16 smem[73728];
  float* Gs = (float*)smem;  // [128][132] aliases (dead during epilogue)

  const int tid = threadIdx.x;
  const int lane = tid & 63;
  const int wave = tid >> 6;
  const int wg = blockIdx.x;
  const int layer = wg >> 6;
  const int sub = wg & 63;
  const int b0 = (sub >> 5) * 128;
  const int h0 = (sub & 31) * 32;

  const int NC = (layer == 0) ? 17 : 32;
  const int T0 = (layer == 0) ? 1 : 16;
  const u16* Wsl = Wp + ((layer == 0) ? 0u : (4456448u + (u32)(layer - 1) * 8388608u))
                 + (u32)(sub & 31) * (u32)NC * 8192u;

  const int nn = tid & 31;
  float bias_r[4];
#pragma unroll
  for (int g = 0; g < 4; ++g) bias_r[g] = biasc[layer * G4 + g * HDIM + h0 + nn];

  const int r0 = (tid >> 5) * 8;
  float cst[8];
#pragma unroll
  for (int k = 0; k < 8; ++k) cst[k] = 0.0f;

  const int opu0 = (wave * 2) * 512 + lane * 8;   // u16 units, op 0
  const int opu1 = opu0 + 512;                    // op 1

  const int mb = (wave & 3) * 32;
  const int nbase = (wave >> 2) * 64;
  const int lrow = lane & 15;
  const int lcb0 = (lane >> 4) << 4;
  const int lswz = (lane & 7) << 4;

  u32* bar_arrive = barr;
  u32* bar_release = barr + 32;

  for (int s = 0; s < TLEN + 3; ++s) {
    const int t = s - layer;
    if (t >= 0 && t < TLEN) {
      const u16* aBase0 = ((layer == 0) ? (xT + (u32)t * 16384u)
                                        : (hbuf + (u32)((layer - 1) * 2 + (t & 1)) * 262144u))
                        + b0 * 64;
      const u16* aBase1 = hbuf + (u32)(layer * 2 + ((t + 1) & 1)) * 262144u + b0 * 64;

      f32x4 acc[2][4];
#pragma unroll
      for (int mt = 0; mt < 2; ++mt)
#pragma unroll
        for (int nt = 0; nt < 4; ++nt) acc[mt][nt] = (f32x4)(0.0f);

      auto issueA = [&](int c, int slot) {
        const u16* src = (c < T0) ? (aBase0 + c * 16384) : (aBase1 + (c - T0) * 16384);
        gl_lds16(src + opu0, smem + slot * 8192 + (wave * 2) * 512);
        gl_lds16(src + opu1, smem + slot * 8192 + (wave * 2 + 1) * 512);
      };
      auto issueB = [&](int c, int slot) {
        const u16* src = Wsl + c * 8192;
        gl_lds16(src + opu0, smem + 32768 + slot * 8192 + (wave * 2) * 512);
        gl_lds16(src + opu1, smem + 32768 + slot * 8192 + (wave * 2 + 1) * 512);
      };

      // prologue (ages must match steady-state pattern):
      issueB(0, 0);
      issueB(1, 1);
      issueA(0, 0); issueB(2, 2);
      issueA(1, 1); issueB(3, 3);

      for (int c = 0; c < NC; ++c) {
        // steady issue: A lead 2, B lead 4; clamp source in tail, slots are safe-dead
        {
          int ca = c + 2; int cca = (ca < NC) ? ca : (NC - 1);
          issueA(cca, ca & 3);
          int cb = c + 4; int ccb = (cb < NC) ? cb : (NC - 1);
          issueB(ccb, cb % 5);
        }
        // retire chunk c's A+B; keep A(c+1..c+2), B(c+2..c+4) in flight (10 instrs)
        asm volatile("s_waitcnt vmcnt(10)" ::: "memory");
        __builtin_amdgcn_s_barrier();

        const char* Abuf = (const char*)smem + (c & 3) * 16384;
        const char* Bbuf = (const char*)smem + 65536 + (c % 5) * 16384;
        bf16x8 a[2][2], b[2][4];
#pragma unroll
        for (int ks = 0; ks < 2; ++ks) {
#pragma unroll
          for (int mt = 0; mt < 2; ++mt) {
            int row = mb + mt * 16 + lrow;
            a[ks][mt] = *(const bf16x8*)(Abuf + row * 128 + ((ks * 64 + lcb0) ^ lswz));
          }
#pragma unroll
          for (int nt = 0; nt < 4; ++nt) {
            int j = nbase + nt * 16 + lrow;
            b[ks][nt] = *(const bf16x8*)(Bbuf + j * 128 + ((ks * 64 + lcb0) ^ lswz));
          }
        }
#pragma unroll
        for (int ks = 0; ks < 2; ++ks)
#pragma unroll
          for (int mt = 0; mt < 2; ++mt)
#pragma unroll
            for (int nt = 0; nt < 4; ++nt)
              acc[mt][nt] = __builtin_amdgcn_mfma_f32_16x16x32_bf16(a[ks][mt], b[ks][nt], acc[mt][nt], 0, 0, 0);

        __builtin_amdgcn_s_barrier();  // reads done before next chunk's loads land
      }

      asm volatile("s_waitcnt vmcnt(0)" ::: "memory");  // drain dummies before Gs alias
      __syncthreads();

      // dump gate tiles to LDS (D layout: col=lane&15, row=(lane>>4)*4+r)
#pragma unroll
      for (int mt = 0; mt < 2; ++mt)
#pragma unroll
        for (int nt = 0; nt < 4; ++nt) {
          int row = mb + mt * 16 + (lane >> 4) * 4;
          int col = nbase + nt * 16 + (lane & 15);
#pragma unroll
          for (int r = 0; r < 4; ++r) Gs[(row + r) * 132 + col] = acc[mt][nt][r];
        }
      __syncthreads();

      // LSTM cell update; c stays in registers. h chunk-major, swizzle baked.
      u16* outSlot = hbuf + (u32)(layer * 2 + (t & 1)) * 262144u;
      const int hcol = h0 + nn;
      const int j2 = hcol >> 6;
      const int colin = hcol & 63;
#pragma unroll
      for (int k = 0; k < 8; ++k) {
        int r = r0 + k;
        float gi = Gs[r * 132 + nn] + bias_r[0];
        float gf = Gs[r * 132 + 32 + nn] + bias_r[1];
        float gg = Gs[r * 132 + 64 + nn] + bias_r[2];
        float go = Gs[r * 132 + 96 + nn] + bias_r[3];
        float iv = sigm(gi), fv = sigm(gf), gv = tanh_(gg), ov = sigm(go);
        float cv = fv * cst[k] + iv * gv;
        cst[k] = cv;
        float hv = ov * tanh_(cv);
        int b = b0 + r;
        bf16 hb = __float2bfloat16(hv);
        outSlot[j2 * 16384 + b * 64 + (colin ^ ((b & 7) << 3))] = *(u16*)&hb;
        if (layer == 3) {
          // non-temporal: don't let the output stream evict weights from L3
          __builtin_nontemporal_store(hv, &out[((size_t)b * TLEN + t) * HDIM + hcol]);
          if (t == TLEN - 1)
            __builtin_nontemporal_store(cv, &out[OUT_HT + (size_t)b * HDIM + hcol]);
        }
      }
    }
    if (s < TLEN + 2) gbar(bar_arrive, bar_release, (u32)(s + 1), tid);
  }
}

// ---------- host ----------

extern "C" void kernel_launch(void* const* d_in, const int* in_sizes, int n_in,
                              void* d_out, int out_size, void* d_ws, size_t ws_size,
                              hipStream_t stream) {
  const float* x = (const float*)d_in[0];
  const float* Wih[4] = {(const float*)d_in[1], (const float*)d_in[5],
                         (const float*)d_in[9], (const float*)d_in[13]};
  const float* Whh[4] = {(const float*)d_in[2], (const float*)d_in[6],
                         (const float*)d_in[10], (const float*)d_in[14]};
  const float* bih[4] = {(const float*)d_in[3], (const float*)d_in[7],
                         (const float*)d_in[11], (const float*)d_in[15]};
  const float* bhh[4] = {(const float*)d_in[4], (const float*)d_in[8],
                         (const float*)d_in[12], (const float*)d_in[16]};

  char* ws = (char*)d_ws;
  bf16* Wp = (bf16*)(ws + WS_WP);
  float* biasc = (float*)(ws + WS_BIAS);
  bf16* xT = (bf16*)(ws + WS_XT);
  u16* hbuf = (u16*)(ws + WS_H);
  u32* barr = (u32*)(ws + WS_BAR);
  float* out = (float*)d_out;

  for (int l = 0; l < 4; ++l) {
    int NC = (l == 0) ? 17 : 32;
    int din = (l == 0) ? 64 : 1024;
    bf16* dst = Wp + ((l == 0) ? 0 : (4456448 + (size_t)(l - 1) * 8388608));
    int total = 32 * NC * 128 * 64;
    pack_w<<<(total + 255) / 256, 256, 0, stream>>>(Wih[l], Whh[l], dst, NC, din);
    pack_bias<<<16, 256, 0, stream>>>(bih[l], bhh[l], biasc + l * 4096);
  }
  pack_x<<<(TLEN * BATCH * 64 + 255) / 256, 256, 0, stream>>>(x, xT);
  hipMemsetAsync(ws + WS_H, 0, 4194304u + 256u, stream);

  void* args[] = {(void*)&Wp, (void*)&biasc, (void*)&xT, (void*)&hbuf, (void*)&out, (void*)&barr};
  hipLaunchCooperativeKernel((void*)lstm_main, dim3(256), dim3(512), args, 0, stream);
}

// Round 6
// 3274.028 us; speedup vs baseline: 1.0455x; 1.0455x over previous
//
#include <hip/hip_runtime.h>
#include <hip/hip_bf16.h>

typedef __hip_bfloat16 bf16;
typedef unsigned short u16;
typedef unsigned int u32;
typedef __attribute__((ext_vector_type(8))) short bf16x8;
typedef __attribute__((ext_vector_type(4))) float f32x4;

// Problem constants
#define BATCH 256
#define TLEN 100
#define HDIM 1024
#define G4 4096
#define OUT_HT (BATCH * TLEN * HDIM)    // float offset of c4 section in d_out

// Workspace layout (byte offsets).
#define WS_WP 0u
#define WS_BIAS 59244544u   // f32 [4][4096]
#define WS_XT 59310080u     // bf16 chunk-major [100][256][64], swizzle baked
#define WS_H 62586880u      // bf16 [8 slots][16 chunks][256][64], swizzle baked
#define WS_BAR (WS_H + 4194304u)

__device__ __forceinline__ float sigm(float x) { return 1.0f / (1.0f + __expf(-x)); }
__device__ __forceinline__ float tanh_(float x) { return 2.0f / (1.0f + __expf(-2.0f * x)) - 1.0f; }

__device__ __forceinline__ void gl_lds16(const void* g, void* l) {
  __builtin_amdgcn_global_load_lds((const __attribute__((address_space(1))) u32*)g,
                                   (__attribute__((address_space(3))) u32*)l, 16, 0, 0);
}

// Lean global barrier (proven R2-R4): monotone release epoch, one ACQ_REL RMW per WG.
__device__ __forceinline__ void gbar(u32* arrive, u32* release, u32 epoch, int tid) {
  __syncthreads();
  if (tid == 0) {
    u32 old = __hip_atomic_fetch_add(arrive, 1u, __ATOMIC_ACQ_REL, __HIP_MEMORY_SCOPE_AGENT);
    if (old == 255u) {
      __hip_atomic_store(arrive, 0u, __ATOMIC_RELAXED, __HIP_MEMORY_SCOPE_AGENT);
      __hip_atomic_store(release, epoch, __ATOMIC_RELEASE, __HIP_MEMORY_SCOPE_AGENT);
    } else {
      while (__hip_atomic_load(release, __ATOMIC_RELAXED, __HIP_MEMORY_SCOPE_AGENT) < epoch)
        __builtin_amdgcn_s_sleep(2);
      __builtin_amdgcn_fence(__ATOMIC_ACQUIRE, "agent");
    }
  }
  __syncthreads();
}

// ---------- setup kernels (unchanged, proven) ----------

__global__ void pack_w(const float* __restrict__ wih, const float* __restrict__ whh,
                       bf16* __restrict__ dst, int NC, int din) {
  int i = blockIdx.x * 256 + threadIdx.x;
  if (i >= 32 * NC * 128 * 64) return;
  int k6 = i & 63;
  int r = (i >> 6) & 127;
  int jc = i >> 13;
  int c = jc % NC;
  int j = jc / NC;
  int grow = ((r >> 5) << 10) + j * 32 + (r & 31);
  int k = c * 64 + k6;
  float v = (k < din) ? wih[grow * din + k] : whh[(grow << 10) + (k - din)];
  dst[(jc << 13) + (r << 6) + (k6 ^ ((r & 7) << 3))] = __float2bfloat16(v);
}

__global__ void pack_bias(const float* __restrict__ a, const float* __restrict__ b,
                          float* __restrict__ dst) {
  int i = blockIdx.x * 256 + threadIdx.x;
  if (i < G4) dst[i] = a[i] + b[i];
}

__global__ void pack_x(const float* __restrict__ x, bf16* __restrict__ xT) {
  int i = blockIdx.x * 256 + threadIdx.x;
  if (i >= TLEN * BATCH * 64) return;
  int k = i & 63;
  int b = (i >> 6) & 255;
  int t = i >> 14;
  xT[(t << 14) + (b << 6) + (k ^ ((b & 7) << 3))] = __float2bfloat16(x[(b * TLEN + t) * 64 + k]);
}

// ---------- main persistent pipelined kernel ----------
// R4 chassis verbatim (512 thr, rings, vmcnt(10), 2 barriers/chunk, wg>>6 decode).
// ONLY change: 8 waves re-gridded 2m x 2n x 2k (split-K). Each wave: 64x64 tile,
// half K-window per chunk -> 8 ds_read_b128 + 16 MFMA per chunk (was 12 + 16).
// Per-CU LDS reads/chunk: 96KB -> 64KB. Epilogue sums K-halves via G0+G1.

__global__ void __launch_bounds__(512, 2)
lstm_main(const u16* __restrict__ Wp, const float* __restrict__ biasc,
          const u16* __restrict__ xT, u16* __restrict__ hbuf,
          float* __restrict__ out, u32* __restrict__ barr) {
  // A bufs: u16 [4][8192] @ 0 (64KB). B bufs: u16 [5][8192] @ 32768 (80KB). Total 144KB.
  // Epilogue aliases: G0 f32[128][132] @ 0, G1 @ byte 67584 (132KB total, post-drain).
  __shared__ __align__(16) u16 smem[73728];

  const int tid = threadIdx.x;
  const int lane = tid & 63;
  const int wave = tid >> 6;
  const int wg = blockIdx.x;
  const int layer = wg >> 6;
  const int sub = wg & 63;
  const int b0 = (sub >> 5) * 128;
  const int h0 = (sub & 31) * 32;

  const int NC = (layer == 0) ? 17 : 32;
  const int T0 = (layer == 0) ? 1 : 16;
  const u16* Wsl = Wp + ((layer == 0) ? 0u : (4456448u + (u32)(layer - 1) * 8388608u))
                 + (u32)(sub & 31) * (u32)NC * 8192u;

  const int nn = tid & 31;
  float bias_r[4];
#pragma unroll
  for (int g = 0; g < 4; ++g) bias_r[g] = biasc[layer * G4 + g * HDIM + h0 + nn];

  const int r0 = (tid >> 5) * 8;
  float cst[8];
#pragma unroll
  for (int k = 0; k < 8; ++k) cst[k] = 0.0f;

  const int opu0 = (wave * 2) * 512 + lane * 8;   // u16 units, op 0
  const int opu1 = opu0 + 512;                    // op 1

  // split-K wave grid: 2m x 2n x 2k
  const int mh = (wave >> 2) & 1;
  const int nh = (wave >> 1) & 1;
  const int kh = wave & 1;
  const int lrow = lane & 15;
  const int lswz = (lane & 7) << 4;
  const int kbyte = kh * 64 + ((lane >> 4) << 4);  // byte col within 128B row
  const int kx = kbyte ^ lswz;

  float* G0 = (float*)smem;                     // [128][132]
  float* G1 = (float*)((char*)smem + 67584);    // [128][132]

  u32* bar_arrive = barr;
  u32* bar_release = barr + 32;

  for (int s = 0; s < TLEN + 3; ++s) {
    const int t = s - layer;
    if (t >= 0 && t < TLEN) {
      const u16* aBase0 = ((layer == 0) ? (xT + (u32)t * 16384u)
                                        : (hbuf + (u32)((layer - 1) * 2 + (t & 1)) * 262144u))
                        + b0 * 64;
      const u16* aBase1 = hbuf + (u32)(layer * 2 + ((t + 1) & 1)) * 262144u + b0 * 64;

      f32x4 acc[4][4];
#pragma unroll
      for (int mt = 0; mt < 4; ++mt)
#pragma unroll
        for (int nt = 0; nt < 4; ++nt) acc[mt][nt] = (f32x4)(0.0f);

      auto issueA = [&](int c, int slot) {
        const u16* src = (c < T0) ? (aBase0 + c * 16384) : (aBase1 + (c - T0) * 16384);
        gl_lds16(src + opu0, smem + slot * 8192 + (wave * 2) * 512);
        gl_lds16(src + opu1, smem + slot * 8192 + (wave * 2 + 1) * 512);
      };
      auto issueB = [&](int c, int slot) {
        const u16* src = Wsl + c * 8192;
        gl_lds16(src + opu0, smem + 32768 + slot * 8192 + (wave * 2) * 512);
        gl_lds16(src + opu1, smem + 32768 + slot * 8192 + (wave * 2 + 1) * 512);
      };

      // prologue (verbatim R4)
      issueB(0, 0);
      issueB(1, 1);
      issueA(0, 0); issueB(2, 2);
      issueA(1, 1); issueB(3, 3);

      for (int c = 0; c < NC; ++c) {
        {
          int ca = c + 2; int cca = (ca < NC) ? ca : (NC - 1);
          issueA(cca, ca & 3);
          int cb = c + 4; int ccb = (cb < NC) ? cb : (NC - 1);
          issueB(ccb, cb % 5);
        }
        asm volatile("s_waitcnt vmcnt(10)" ::: "memory");
        __builtin_amdgcn_s_barrier();

        const char* Abuf = (const char*)smem + (c & 3) * 16384;
        const char* Bbuf = (const char*)smem + 65536 + (c % 5) * 16384;
        bf16x8 a[4], b[4];
#pragma unroll
        for (int mt = 0; mt < 4; ++mt) {
          int row = mh * 64 + mt * 16 + lrow;
          a[mt] = *(const bf16x8*)(Abuf + row * 128 + kx);
        }
#pragma unroll
        for (int nt = 0; nt < 4; ++nt) {
          int row = nh * 64 + nt * 16 + lrow;
          b[nt] = *(const bf16x8*)(Bbuf + row * 128 + kx);
        }
#pragma unroll
        for (int mt = 0; mt < 4; ++mt)
#pragma unroll
          for (int nt = 0; nt < 4; ++nt)
            acc[mt][nt] = __builtin_amdgcn_mfma_f32_16x16x32_bf16(a[mt], b[nt], acc[mt][nt], 0, 0, 0);

        __builtin_amdgcn_s_barrier();  // reads done before next chunk's loads land
      }

      asm volatile("s_waitcnt vmcnt(0)" ::: "memory");  // drain (incl. dummies) before G alias
      __syncthreads();

      // dump gate tiles (16x16 D layout: col=lane&15, row=(lane>>4)*4+r) into G{kh}
      float* Gw = kh ? G1 : G0;
#pragma unroll
      for (int mt = 0; mt < 4; ++mt)
#pragma unroll
        for (int nt = 0; nt < 4; ++nt) {
          int row = mh * 64 + mt * 16 + (lane >> 4) * 4;
          int col = nh * 64 + nt * 16 + (lane & 15);
#pragma unroll
          for (int r = 0; r < 4; ++r) Gw[(row + r) * 132 + col] = acc[mt][nt][r];
        }
      __syncthreads();

      // LSTM cell update; c stays in registers. Gates = G0 + G1 (K-halves) + bias.
      u16* outSlot = hbuf + (u32)(layer * 2 + (t & 1)) * 262144u;
      const int hcol = h0 + nn;
      const int j2 = hcol >> 6;
      const int colin = hcol & 63;
#pragma unroll
      for (int k = 0; k < 8; ++k) {
        int r = r0 + k;
        float gi = G0[r * 132 + nn]      + G1[r * 132 + nn]      + bias_r[0];
        float gf = G0[r * 132 + 32 + nn] + G1[r * 132 + 32 + nn] + bias_r[1];
        float gg = G0[r * 132 + 64 + nn] + G1[r * 132 + 64 + nn] + bias_r[2];
        float go = G0[r * 132 + 96 + nn] + G1[r * 132 + 96 + nn] + bias_r[3];
        float iv = sigm(gi), fv = sigm(gf), gv = tanh_(gg), ov = sigm(go);
        float cv = fv * cst[k] + iv * gv;
        cst[k] = cv;
        float hv = ov * tanh_(cv);
        int b = b0 + r;
        bf16 hb = __float2bfloat16(hv);
        outSlot[j2 * 16384 + b * 64 + (colin ^ ((b & 7) << 3))] = *(u16*)&hb;
        if (layer == 3) {
          out[((size_t)b * TLEN + t) * HDIM + hcol] = hv;
          if (t == TLEN - 1) out[OUT_HT + (size_t)b * HDIM + hcol] = cv;
        }
      }
    }
    if (s < TLEN + 2) gbar(bar_arrive, bar_release, (u32)(s + 1), tid);
  }
}

// ---------- host ----------

extern "C" void kernel_launch(void* const* d_in, const int* in_sizes, int n_in,
                              void* d_out, int out_size, void* d_ws, size_t ws_size,
                              hipStream_t stream) {
  const float* x = (const float*)d_in[0];
  const float* Wih[4] = {(const float*)d_in[1], (const float*)d_in[5],
                         (const float*)d_in[9], (const float*)d_in[13]};
  const float* Whh[4] = {(const float*)d_in[2], (const float*)d_in[6],
                         (const float*)d_in[10], (const float*)d_in[14]};
  const float* bih[4] = {(const float*)d_in[3], (const float*)d_in[7],
                         (const float*)d_in[11], (const float*)d_in[15]};
  const float* bhh[4] = {(const float*)d_in[4], (const float*)d_in[8],
                         (const float*)d_in[12], (const float*)d_in[16]};

  char* ws = (char*)d_ws;
  bf16* Wp = (bf16*)(ws + WS_WP);
  float* biasc = (float*)(ws + WS_BIAS);
  bf16* xT = (bf16*)(ws + WS_XT);
  u16* hbuf = (u16*)(ws + WS_H);
  u32* barr = (u32*)(ws + WS_BAR);
  float* out = (float*)d_out;

  for (int l = 0; l < 4; ++l) {
    int NC = (l == 0) ? 17 : 32;
    int din = (l == 0) ? 64 : 1024;
    bf16* dst = Wp + ((l == 0) ? 0 : (4456448 + (size_t)(l - 1) * 8388608));
    int total = 32 * NC * 128 * 64;
    pack_w<<<(total + 255) / 256, 256, 0, stream>>>(Wih[l], Whh[l], dst, NC, din);
    pack_bias<<<16, 256, 0, stream>>>(bih[l], bhh[l], biasc + l * 4096);
  }
  pack_x<<<(TLEN * BATCH * 64 + 255) / 256, 256, 0, stream>>>(x, xT);
  hipMemsetAsync(ws + WS_H, 0, 4194304u + 256u, stream);

  void* args[] = {(void*)&Wp, (void*)&biasc, (void*)&xT, (void*)&hbuf, (void*)&out, (void*)&barr};
  hipLaunchCooperativeKernel((void*)lstm_main, dim3(256), dim3(512), args, 0, stream);
}

// Round 7
// 3165.975 us; speedup vs baseline: 1.0812x; 1.0341x over previous
//
#include <hip/hip_runtime.h>
#include <hip/hip_bf16.h>

typedef __hip_bfloat16 bf16;
typedef unsigned short u16;
typedef unsigned int u32;
typedef __attribute__((ext_vector_type(8))) short bf16x8;
typedef __attribute__((ext_vector_type(4))) float f32x4;

// Problem constants
#define BATCH 256
#define TLEN 100
#define HDIM 1024
#define G4 4096
#define OUT_HT (BATCH * TLEN * HDIM)    // float offset of c4 section in d_out

// Workspace layout (byte offsets).
#define WS_WP 0u
#define WS_BIAS 59244544u   // f32 [4][4096]
#define WS_XT 59310080u     // bf16 chunk-major [100][256][64], swizzle baked
#define WS_H 62586880u      // bf16 [8 slots][16 chunks][256][64], swizzle baked
#define WS_FLAGS (WS_H + 4194304u)  // u32 [4 layers][2 btiles][32 slices]

__device__ __forceinline__ float sigm(float x) { return 1.0f / (1.0f + __expf(-x)); }
__device__ __forceinline__ float tanh_(float x) { return 2.0f / (1.0f + __expf(-2.0f * x)) - 1.0f; }

__device__ __forceinline__ void gl_lds16(const void* g, void* l) {
  __builtin_amdgcn_global_load_lds((const __attribute__((address_space(1))) u32*)g,
                                   (__attribute__((address_space(3))) u32*)l, 16, 0, 0);
}

// ---------- setup kernels (unchanged, proven) ----------

__global__ void pack_w(const float* __restrict__ wih, const float* __restrict__ whh,
                       bf16* __restrict__ dst, int NC, int din) {
  int i = blockIdx.x * 256 + threadIdx.x;
  if (i >= 32 * NC * 128 * 64) return;
  int k6 = i & 63;
  int r = (i >> 6) & 127;
  int jc = i >> 13;
  int c = jc % NC;
  int j = jc / NC;
  int grow = ((r >> 5) << 10) + j * 32 + (r & 31);
  int k = c * 64 + k6;
  float v = (k < din) ? wih[grow * din + k] : whh[(grow << 10) + (k - din)];
  dst[(jc << 13) + (r << 6) + (k6 ^ ((r & 7) << 3))] = __float2bfloat16(v);
}

__global__ void pack_bias(const float* __restrict__ a, const float* __restrict__ b,
                          float* __restrict__ dst) {
  int i = blockIdx.x * 256 + threadIdx.x;
  if (i < G4) dst[i] = a[i] + b[i];
}

__global__ void pack_x(const float* __restrict__ x, bf16* __restrict__ xT) {
  int i = blockIdx.x * 256 + threadIdx.x;
  if (i >= TLEN * BATCH * 64) return;
  int k = i & 63;
  int b = (i >> 6) & 255;
  int t = i >> 14;
  xT[(t << 14) + (b << 6) + (k ^ ((b & 7) << 3))] = __float2bfloat16(x[(b * TLEN + t) * 64 + k]);
}

// ---------- main persistent kernel: flag-synced dependency pipeline ----------
// R6 body verbatim (512 thr, split-K 2m2n2k waves, rings, vmcnt(10), 2 barriers/chunk).
// ONLY change: grid barrier -> per-WG epoch flags (producer/consumer dependency graph).
// WG (layer, bt, j) before timestep t waits:
//   RAW: prev-layer same-bt flags >= t+1; own-layer same-bt flags >= t.
//   WAR (h-ring depth 2): next-layer same-bt flags >= t-1.
// Publishes flag = t+1 (RELEASE) after its h/out stores. No RMW, no rendezvous.

__global__ void __launch_bounds__(512, 2)
lstm_main(const u16* __restrict__ Wp, const float* __restrict__ biasc,
          const u16* __restrict__ xT, u16* __restrict__ hbuf,
          float* __restrict__ out, u32* __restrict__ flags) {
  // A bufs: u16 [4][8192] @ 0 (64KB). B bufs: u16 [5][8192] @ 32768 (80KB). Total 144KB.
  // Epilogue aliases: G0 f32[128][132] @ 0, G1 @ byte 67584 (post-drain).
  __shared__ __align__(16) u16 smem[73728];

  const int tid = threadIdx.x;
  const int lane = tid & 63;
  const int wave = tid >> 6;
  const int wg = blockIdx.x;
  const int layer = wg >> 6;
  const int sub = wg & 63;
  const int bt = sub >> 5;
  const int b0 = bt * 128;
  const int h0 = (sub & 31) * 32;

  const int NC = (layer == 0) ? 17 : 32;
  const int T0 = (layer == 0) ? 1 : 16;
  const u16* Wsl = Wp + ((layer == 0) ? 0u : (4456448u + (u32)(layer - 1) * 8388608u))
                 + (u32)(sub & 31) * (u32)NC * 8192u;

  const int nn = tid & 31;
  float bias_r[4];
#pragma unroll
  for (int g = 0; g < 4; ++g) bias_r[g] = biasc[layer * G4 + g * HDIM + h0 + nn];

  const int r0 = (tid >> 5) * 8;
  float cst[8];
#pragma unroll
  for (int k = 0; k < 8; ++k) cst[k] = 0.0f;

  const int opu0 = (wave * 2) * 512 + lane * 8;   // u16 units, op 0
  const int opu1 = opu0 + 512;                    // op 1

  // split-K wave grid: 2m x 2n x 2k (R6, proven)
  const int mh = (wave >> 2) & 1;
  const int nh = (wave >> 1) & 1;
  const int kh = wave & 1;
  const int lrow = lane & 15;
  const int lswz = (lane & 7) << 4;
  const int kbyte = kh * 64 + ((lane >> 4) << 4);
  const int kx = kbyte ^ lswz;

  float* G0 = (float*)smem;                     // [128][132]
  float* G1 = (float*)((char*)smem + 67584);    // [128][132]

  // flag pointers (clamped index math; guarded by need* predicates)
  u32* myflag = flags + (layer * 2 + bt) * 32 + (sub & 31);
  const u32 jj = lane & 31;
  const u32* pPrev = flags + (((layer > 0 ? layer - 1 : 0) * 2 + bt) * 32) + jj;
  const u32* pNext = flags + (((layer < 3 ? layer + 1 : 3) * 2 + bt) * 32) + jj;
  const u32* pOwn  = flags + ((layer * 2 + bt) * 32) + jj;

  for (int t = 0; t < TLEN; ++t) {
    // ---- dependency wait (wave 0 polls; no RMW, no rendezvous) ----
    if (wave == 0) {
      const bool needP = (layer > 0) && (lane < 32);
      const bool needN = (layer < 3) && (lane < 32) && (t >= 2);
      const bool needO = (lane >= 32) && (t >= 1);
      while (true) {
        bool ok = true;
        if (needP) ok &= (__hip_atomic_load(pPrev, __ATOMIC_RELAXED, __HIP_MEMORY_SCOPE_AGENT) >= (u32)(t + 1));
        if (needN) ok &= (__hip_atomic_load(pNext, __ATOMIC_RELAXED, __HIP_MEMORY_SCOPE_AGENT) >= (u32)(t - 1));
        if (needO) ok &= (__hip_atomic_load(pOwn,  __ATOMIC_RELAXED, __HIP_MEMORY_SCOPE_AGENT) >= (u32)t);
        if (__all(ok)) break;
        __builtin_amdgcn_s_sleep(1);
      }
      __builtin_amdgcn_fence(__ATOMIC_ACQUIRE, "agent");
    }
    __syncthreads();

    const u16* aBase0 = ((layer == 0) ? (xT + (u32)t * 16384u)
                                      : (hbuf + (u32)((layer - 1) * 2 + (t & 1)) * 262144u))
                      + b0 * 64;
    const u16* aBase1 = hbuf + (u32)(layer * 2 + ((t + 1) & 1)) * 262144u + b0 * 64;

    f32x4 acc[4][4];
#pragma unroll
    for (int mt = 0; mt < 4; ++mt)
#pragma unroll
      for (int nt = 0; nt < 4; ++nt) acc[mt][nt] = (f32x4)(0.0f);

    auto issueA = [&](int c, int slot) {
      const u16* src = (c < T0) ? (aBase0 + c * 16384) : (aBase1 + (c - T0) * 16384);
      gl_lds16(src + opu0, smem + slot * 8192 + (wave * 2) * 512);
      gl_lds16(src + opu1, smem + slot * 8192 + (wave * 2 + 1) * 512);
    };
    auto issueB = [&](int c, int slot) {
      const u16* src = Wsl + c * 8192;
      gl_lds16(src + opu0, smem + 32768 + slot * 8192 + (wave * 2) * 512);
      gl_lds16(src + opu1, smem + 32768 + slot * 8192 + (wave * 2 + 1) * 512);
    };

    // prologue (verbatim R4/R6)
    issueB(0, 0);
    issueB(1, 1);
    issueA(0, 0); issueB(2, 2);
    issueA(1, 1); issueB(3, 3);

    for (int c = 0; c < NC; ++c) {
      {
        int ca = c + 2; int cca = (ca < NC) ? ca : (NC - 1);
        issueA(cca, ca & 3);
        int cb = c + 4; int ccb = (cb < NC) ? cb : (NC - 1);
        issueB(ccb, cb % 5);
      }
      asm volatile("s_waitcnt vmcnt(10)" ::: "memory");
      __builtin_amdgcn_s_barrier();

      const char* Abuf = (const char*)smem + (c & 3) * 16384;
      const char* Bbuf = (const char*)smem + 65536 + (c % 5) * 16384;
      bf16x8 a[4], b[4];
#pragma unroll
      for (int mt = 0; mt < 4; ++mt) {
        int row = mh * 64 + mt * 16 + lrow;
        a[mt] = *(const bf16x8*)(Abuf + row * 128 + kx);
      }
#pragma unroll
      for (int nt = 0; nt < 4; ++nt) {
        int row = nh * 64 + nt * 16 + lrow;
        b[nt] = *(const bf16x8*)(Bbuf + row * 128 + kx);
      }
#pragma unroll
      for (int mt = 0; mt < 4; ++mt)
#pragma unroll
        for (int nt = 0; nt < 4; ++nt)
          acc[mt][nt] = __builtin_amdgcn_mfma_f32_16x16x32_bf16(a[mt], b[nt], acc[mt][nt], 0, 0, 0);

      __builtin_amdgcn_s_barrier();  // reads done before next chunk's loads land
    }

    asm volatile("s_waitcnt vmcnt(0)" ::: "memory");  // drain (incl. dummies) before G alias
    __syncthreads();

    // dump gate tiles (16x16 D layout: col=lane&15, row=(lane>>4)*4+r) into G{kh}
    float* Gw = kh ? G1 : G0;
#pragma unroll
    for (int mt = 0; mt < 4; ++mt)
#pragma unroll
      for (int nt = 0; nt < 4; ++nt) {
        int row = mh * 64 + mt * 16 + (lane >> 4) * 4;
        int col = nh * 64 + nt * 16 + (lane & 15);
#pragma unroll
        for (int r = 0; r < 4; ++r) Gw[(row + r) * 132 + col] = acc[mt][nt][r];
      }
    __syncthreads();

    // LSTM cell update; c stays in registers. Gates = G0 + G1 (K-halves) + bias.
    u16* outSlot = hbuf + (u32)(layer * 2 + (t & 1)) * 262144u;
    const int hcol = h0 + nn;
    const int j2 = hcol >> 6;
    const int colin = hcol & 63;
#pragma unroll
    for (int k = 0; k < 8; ++k) {
      int r = r0 + k;
      float gi = G0[r * 132 + nn]      + G1[r * 132 + nn]      + bias_r[0];
      float gf = G0[r * 132 + 32 + nn] + G1[r * 132 + 32 + nn] + bias_r[1];
      float gg = G0[r * 132 + 64 + nn] + G1[r * 132 + 64 + nn] + bias_r[2];
      float go = G0[r * 132 + 96 + nn] + G1[r * 132 + 96 + nn] + bias_r[3];
      float iv = sigm(gi), fv = sigm(gf), gv = tanh_(gg), ov = sigm(go);
      float cv = fv * cst[k] + iv * gv;
      cst[k] = cv;
      float hv = ov * tanh_(cv);
      int b = b0 + r;
      bf16 hb = __float2bfloat16(hv);
      outSlot[j2 * 16384 + b * 64 + (colin ^ ((b & 7) << 3))] = *(u16*)&hb;
      if (layer == 3) {
        out[((size_t)b * TLEN + t) * HDIM + hcol] = hv;
        if (t == TLEN - 1) out[OUT_HT + (size_t)b * HDIM + hcol] = cv;
      }
    }

    // ---- publish: all WG stores done -> release epoch ----
    __syncthreads();
    if (tid == 0)
      __hip_atomic_store(myflag, (u32)(t + 1), __ATOMIC_RELEASE, __HIP_MEMORY_SCOPE_AGENT);
  }
}

// ---------- host ----------

extern "C" void kernel_launch(void* const* d_in, const int* in_sizes, int n_in,
                              void* d_out, int out_size, void* d_ws, size_t ws_size,
                              hipStream_t stream) {
  const float* x = (const float*)d_in[0];
  const float* Wih[4] = {(const float*)d_in[1], (const float*)d_in[5],
                         (const float*)d_in[9], (const float*)d_in[13]};
  const float* Whh[4] = {(const float*)d_in[2], (const float*)d_in[6],
                         (const float*)d_in[10], (const float*)d_in[14]};
  const float* bih[4] = {(const float*)d_in[3], (const float*)d_in[7],
                         (const float*)d_in[11], (const float*)d_in[15]};
  const float* bhh[4] = {(const float*)d_in[4], (const float*)d_in[8],
                         (const float*)d_in[12], (const float*)d_in[16]};

  char* ws = (char*)d_ws;
  bf16* Wp = (bf16*)(ws + WS_WP);
  float* biasc = (float*)(ws + WS_BIAS);
  bf16* xT = (bf16*)(ws + WS_XT);
  u16* hbuf = (u16*)(ws + WS_H);
  u32* flags = (u32*)(ws + WS_FLAGS);
  float* out = (float*)d_out;

  for (int l = 0; l < 4; ++l) {
    int NC = (l == 0) ? 17 : 32;
    int din = (l == 0) ? 64 : 1024;
    bf16* dst = Wp + ((l == 0) ? 0 : (4456448 + (size_t)(l - 1) * 8388608));
    int total = 32 * NC * 128 * 64;
    pack_w<<<(total + 255) / 256, 256, 0, stream>>>(Wih[l], Whh[l], dst, NC, din);
    pack_bias<<<16, 256, 0, stream>>>(bih[l], bhh[l], biasc + l * 4096);
  }
  pack_x<<<(TLEN * BATCH * 64 + 255) / 256, 256, 0, stream>>>(x, xT);
  // zero h ring + flags
  hipMemsetAsync(ws + WS_H, 0, 4194304u + 1024u, stream);

  void* args[] = {(void*)&Wp, (void*)&biasc, (void*)&xT, (void*)&hbuf, (void*)&out, (void*)&flags};
  hipLaunchCooperativeKernel((void*)lstm_main, dim3(256), dim3(512), args, 0, stream);
}

// Round 8
// 3094.315 us; speedup vs baseline: 1.1062x; 1.0232x over previous
//
#include <hip/hip_runtime.h>
#include <hip/hip_bf16.h>

typedef __hip_bfloat16 bf16;
typedef unsigned short u16;
typedef unsigned int u32;
typedef __attribute__((ext_vector_type(8))) short bf16x8;
typedef __attribute__((ext_vector_type(4))) float f32x4;

// Problem constants
#define BATCH 256
#define TLEN 100
#define HDIM 1024
#define G4 4096
#define OUT_HT (BATCH * TLEN * HDIM)    // float offset of c4 section in d_out

// Workspace layout (byte offsets).
#define WS_WP 0u
#define WS_BIAS 59244544u   // f32 [4][4096]
#define WS_XT 59310080u     // bf16 chunk-major [100][256][64], swizzle baked
#define WS_H 62586880u      // bf16 [8 slots][16 chunks][256][64], swizzle baked
#define WS_FLAGS (WS_H + 4194304u)  // u32 [4 layers][2 btiles][32 slices]

__device__ __forceinline__ float sigm(float x) { return 1.0f / (1.0f + __expf(-x)); }
__device__ __forceinline__ float tanh_(float x) { return 2.0f / (1.0f + __expf(-2.0f * x)) - 1.0f; }

__device__ __forceinline__ void gl_lds16(const void* g, void* l) {
  __builtin_amdgcn_global_load_lds((const __attribute__((address_space(1))) u32*)g,
                                   (__attribute__((address_space(3))) u32*)l, 16, 0, 0);
}

// ---------- setup kernels (unchanged, proven) ----------

__global__ void pack_w(const float* __restrict__ wih, const float* __restrict__ whh,
                       bf16* __restrict__ dst, int NC, int din) {
  int i = blockIdx.x * 256 + threadIdx.x;
  if (i >= 32 * NC * 128 * 64) return;
  int k6 = i & 63;
  int r = (i >> 6) & 127;
  int jc = i >> 13;
  int c = jc % NC;
  int j = jc / NC;
  int grow = ((r >> 5) << 10) + j * 32 + (r & 31);
  int k = c * 64 + k6;
  float v = (k < din) ? wih[grow * din + k] : whh[(grow << 10) + (k - din)];
  dst[(jc << 13) + (r << 6) + (k6 ^ ((r & 7) << 3))] = __float2bfloat16(v);
}

__global__ void pack_bias(const float* __restrict__ a, const float* __restrict__ b,
                          float* __restrict__ dst) {
  int i = blockIdx.x * 256 + threadIdx.x;
  if (i < G4) dst[i] = a[i] + b[i];
}

__global__ void pack_x(const float* __restrict__ x, bf16* __restrict__ xT) {
  int i = blockIdx.x * 256 + threadIdx.x;
  if (i >= TLEN * BATCH * 64) return;
  int k = i & 63;
  int b = (i >> 6) & 255;
  int t = i >> 14;
  xT[(t << 14) + (b << 6) + (k ^ ((b & 7) << 3))] = __float2bfloat16(x[(b * TLEN + t) * 64 + k]);
}

// ---------- main persistent kernel: flag-synced dependency pipeline ----------
// R7 chassis; ONLY change: ONE s_barrier per chunk (post-MFMA barrier deleted).
// Ring-safety with single barrier (max skew 1 iter): writer slot at iter i+1 vs
// straggler reader at iter i must differ: A ring 4 lead 2 -> (2+1)%4 != 0 OK;
// B ring 5 lead 3 -> (3+1)%5 != 0 OK (lead reduced from 4).
// vmcnt(10) unchanged (re-derived: 10 ops younger than chunk-c's A pair).

__global__ void __launch_bounds__(512, 2)
lstm_main(const u16* __restrict__ Wp, const float* __restrict__ biasc,
          const u16* __restrict__ xT, u16* __restrict__ hbuf,
          float* __restrict__ out, u32* __restrict__ flags) {
  // A bufs: u16 [4][8192] @ 0 (64KB). B bufs: u16 [5][8192] @ 32768 (80KB). Total 144KB.
  // Epilogue aliases: G0 f32[128][132] @ 0, G1 @ byte 67584 (post-drain).
  __shared__ __align__(16) u16 smem[73728];

  const int tid = threadIdx.x;
  const int lane = tid & 63;
  const int wave = tid >> 6;
  const int wg = blockIdx.x;
  const int layer = wg >> 6;
  const int sub = wg & 63;
  const int bt = sub >> 5;
  const int b0 = bt * 128;
  const int h0 = (sub & 31) * 32;

  const int NC = (layer == 0) ? 17 : 32;
  const int T0 = (layer == 0) ? 1 : 16;
  const u16* Wsl = Wp + ((layer == 0) ? 0u : (4456448u + (u32)(layer - 1) * 8388608u))
                 + (u32)(sub & 31) * (u32)NC * 8192u;

  const int nn = tid & 31;
  float bias_r[4];
#pragma unroll
  for (int g = 0; g < 4; ++g) bias_r[g] = biasc[layer * G4 + g * HDIM + h0 + nn];

  const int r0 = (tid >> 5) * 8;
  float cst[8];
#pragma unroll
  for (int k = 0; k < 8; ++k) cst[k] = 0.0f;

  const int opu0 = (wave * 2) * 512 + lane * 8;   // u16 units, op 0
  const int opu1 = opu0 + 512;                    // op 1

  // split-K wave grid: 2m x 2n x 2k (R6/R7, proven)
  const int mh = (wave >> 2) & 1;
  const int nh = (wave >> 1) & 1;
  const int kh = wave & 1;
  const int lrow = lane & 15;
  const int lswz = (lane & 7) << 4;
  const int kbyte = kh * 64 + ((lane >> 4) << 4);
  const int kx = kbyte ^ lswz;

  float* G0 = (float*)smem;                     // [128][132]
  float* G1 = (float*)((char*)smem + 67584);    // [128][132]

  // flag pointers (clamped index math; guarded by need* predicates)
  u32* myflag = flags + (layer * 2 + bt) * 32 + (sub & 31);
  const u32 jj = lane & 31;
  const u32* pPrev = flags + (((layer > 0 ? layer - 1 : 0) * 2 + bt) * 32) + jj;
  const u32* pNext = flags + (((layer < 3 ? layer + 1 : 3) * 2 + bt) * 32) + jj;
  const u32* pOwn  = flags + ((layer * 2 + bt) * 32) + jj;

  for (int t = 0; t < TLEN; ++t) {
    // ---- dependency wait (wave 0 polls; no RMW, no rendezvous) ----
    if (wave == 0) {
      const bool needP = (layer > 0) && (lane < 32);
      const bool needN = (layer < 3) && (lane < 32) && (t >= 2);
      const bool needO = (lane >= 32) && (t >= 1);
      while (true) {
        bool ok = true;
        if (needP) ok &= (__hip_atomic_load(pPrev, __ATOMIC_RELAXED, __HIP_MEMORY_SCOPE_AGENT) >= (u32)(t + 1));
        if (needN) ok &= (__hip_atomic_load(pNext, __ATOMIC_RELAXED, __HIP_MEMORY_SCOPE_AGENT) >= (u32)(t - 1));
        if (needO) ok &= (__hip_atomic_load(pOwn,  __ATOMIC_RELAXED, __HIP_MEMORY_SCOPE_AGENT) >= (u32)t);
        if (__all(ok)) break;
        __builtin_amdgcn_s_sleep(1);
      }
      __builtin_amdgcn_fence(__ATOMIC_ACQUIRE, "agent");
    }
    __syncthreads();

    const u16* aBase0 = ((layer == 0) ? (xT + (u32)t * 16384u)
                                      : (hbuf + (u32)((layer - 1) * 2 + (t & 1)) * 262144u))
                      + b0 * 64;
    const u16* aBase1 = hbuf + (u32)(layer * 2 + ((t + 1) & 1)) * 262144u + b0 * 64;

    f32x4 acc[4][4];
#pragma unroll
    for (int mt = 0; mt < 4; ++mt)
#pragma unroll
      for (int nt = 0; nt < 4; ++nt) acc[mt][nt] = (f32x4)(0.0f);

    auto issueA = [&](int c, int slot) {
      const u16* src = (c < T0) ? (aBase0 + c * 16384) : (aBase1 + (c - T0) * 16384);
      gl_lds16(src + opu0, smem + slot * 8192 + (wave * 2) * 512);
      gl_lds16(src + opu1, smem + slot * 8192 + (wave * 2 + 1) * 512);
    };
    auto issueB = [&](int c, int slot) {
      const u16* src = Wsl + c * 8192;
      gl_lds16(src + opu0, smem + 32768 + slot * 8192 + (wave * 2) * 512);
      gl_lds16(src + opu1, smem + 32768 + slot * 8192 + (wave * 2 + 1) * 512);
    };

    // prologue: chronological B0,A0,B1,A1,B2 (matches steady-state vmcnt ages)
    issueB(0, 0);
    issueA(0, 0);
    issueB(1, 1);
    issueA(1, 1);
    issueB(2, 2);

    for (int c = 0; c < NC; ++c) {
      // steady issue: A lead 2 (ring 4), B lead 3 (ring 5); clamp src in tail
      {
        int ca = c + 2; int cca = (ca < NC) ? ca : (NC - 1);
        issueA(cca, ca & 3);
        int cb = c + 3; int ccb = (cb < NC) ? cb : (NC - 1);
        issueB(ccb, cb % 5);
      }
      // retire chunk c's A+B; keep A(c+1..c+2), B(c+1..c+3) in flight (10 ops)
      asm volatile("s_waitcnt vmcnt(10)" ::: "memory");
      __builtin_amdgcn_s_barrier();   // the ONLY barrier per chunk

      const char* Abuf = (const char*)smem + (c & 3) * 16384;
      const char* Bbuf = (const char*)smem + 65536 + (c % 5) * 16384;
      bf16x8 a[4], b[4];
#pragma unroll
      for (int mt = 0; mt < 4; ++mt) {
        int row = mh * 64 + mt * 16 + lrow;
        a[mt] = *(const bf16x8*)(Abuf + row * 128 + kx);
      }
#pragma unroll
      for (int nt = 0; nt < 4; ++nt) {
        int row = nh * 64 + nt * 16 + lrow;
        b[nt] = *(const bf16x8*)(Bbuf + row * 128 + kx);
      }
#pragma unroll
      for (int mt = 0; mt < 4; ++mt)
#pragma unroll
        for (int nt = 0; nt < 4; ++nt)
          acc[mt][nt] = __builtin_amdgcn_mfma_f32_16x16x32_bf16(a[mt], b[nt], acc[mt][nt], 0, 0, 0);
      // no second barrier: single-barrier ring safety proven (skew <= 1 iter,
      // writer slots (c+3)&3 / (c+4)%5 never alias reader slots c&3 / c%5)
    }

    asm volatile("s_waitcnt vmcnt(0)" ::: "memory");  // drain (incl. dummies) before G alias
    __syncthreads();

    // dump gate tiles (16x16 D layout: col=lane&15, row=(lane>>4)*4+r) into G{kh}
    float* Gw = kh ? G1 : G0;
#pragma unroll
    for (int mt = 0; mt < 4; ++mt)
#pragma unroll
      for (int nt = 0; nt < 4; ++nt) {
        int row = mh * 64 + mt * 16 + (lane >> 4) * 4;
        int col = nh * 64 + nt * 16 + (lane & 15);
#pragma unroll
        for (int r = 0; r < 4; ++r) Gw[(row + r) * 132 + col] = acc[mt][nt][r];
      }
    __syncthreads();

    // LSTM cell update; c stays in registers. Gates = G0 + G1 (K-halves) + bias.
    u16* outSlot = hbuf + (u32)(layer * 2 + (t & 1)) * 262144u;
    const int hcol = h0 + nn;
    const int j2 = hcol >> 6;
    const int colin = hcol & 63;
#pragma unroll
    for (int k = 0; k < 8; ++k) {
      int r = r0 + k;
      float gi = G0[r * 132 + nn]      + G1[r * 132 + nn]      + bias_r[0];
      float gf = G0[r * 132 + 32 + nn] + G1[r * 132 + 32 + nn] + bias_r[1];
      float gg = G0[r * 132 + 64 + nn] + G1[r * 132 + 64 + nn] + bias_r[2];
      float go = G0[r * 132 + 96 + nn] + G1[r * 132 + 96 + nn] + bias_r[3];
      float iv = sigm(gi), fv = sigm(gf), gv = tanh_(gg), ov = sigm(go);
      float cv = fv * cst[k] + iv * gv;
      cst[k] = cv;
      float hv = ov * tanh_(cv);
      int b = b0 + r;
      bf16 hb = __float2bfloat16(hv);
      outSlot[j2 * 16384 + b * 64 + (colin ^ ((b & 7) << 3))] = *(u16*)&hb;
      if (layer == 3) {
        out[((size_t)b * TLEN + t) * HDIM + hcol] = hv;
        if (t == TLEN - 1) out[OUT_HT + (size_t)b * HDIM + hcol] = cv;
      }
    }

    // ---- publish: all WG stores done -> release epoch ----
    __syncthreads();
    if (tid == 0)
      __hip_atomic_store(myflag, (u32)(t + 1), __ATOMIC_RELEASE, __HIP_MEMORY_SCOPE_AGENT);
  }
}

// ---------- host ----------

extern "C" void kernel_launch(void* const* d_in, const int* in_sizes, int n_in,
                              void* d_out, int out_size, void* d_ws, size_t ws_size,
                              hipStream_t stream) {
  const float* x = (const float*)d_in[0];
  const float* Wih[4] = {(const float*)d_in[1], (const float*)d_in[5],
                         (const float*)d_in[9], (const float*)d_in[13]};
  const float* Whh[4] = {(const float*)d_in[2], (const float*)d_in[6],
                         (const float*)d_in[10], (const float*)d_in[14]};
  const float* bih[4] = {(const float*)d_in[3], (const float*)d_in[7],
                         (const float*)d_in[11], (const float*)d_in[15]};
  const float* bhh[4] = {(const float*)d_in[4], (const float*)d_in[8],
                         (const float*)d_in[12], (const float*)d_in[16]};

  char* ws = (char*)d_ws;
  bf16* Wp = (bf16*)(ws + WS_WP);
  float* biasc = (float*)(ws + WS_BIAS);
  bf16* xT = (bf16*)(ws + WS_XT);
  u16* hbuf = (u16*)(ws + WS_H);
  u32* flags = (u32*)(ws + WS_FLAGS);
  float* out = (float*)d_out;

  for (int l = 0; l < 4; ++l) {
    int NC = (l == 0) ? 17 : 32;
    int din = (l == 0) ? 64 : 1024;
    bf16* dst = Wp + ((l == 0) ? 0 : (4456448 + (size_t)(l - 1) * 8388608));
    int total = 32 * NC * 128 * 64;
    pack_w<<<(total + 255) / 256, 256, 0, stream>>>(Wih[l], Whh[l], dst, NC, din);
    pack_bias<<<16, 256, 0, stream>>>(bih[l], bhh[l], biasc + l * 4096);
  }
  pack_x<<<(TLEN * BATCH * 64 + 255) / 256, 256, 0, stream>>>(x, xT);
  // zero h ring + flags
  hipMemsetAsync(ws + WS_H, 0, 4194304u + 1024u, stream);

  void* args[] = {(void*)&Wp, (void*)&biasc, (void*)&xT, (void*)&hbuf, (void*)&out, (void*)&flags};
  hipLaunchCooperativeKernel((void*)lstm_main, dim3(256), dim3(512), args, 0, stream);
}